// Round 1
// baseline (1315.609 us; speedup 1.0000x reference)
//
#include <hip/hip_runtime.h>
#include <stdint.h>

typedef short v8s __attribute__((ext_vector_type(8)));
typedef float f4 __attribute__((ext_vector_type(4)));

#define CUT1 19997
#define CUT2 39997
#define CUT3 199997
#define NROWS 1024
#define LDP 1360   // packed proj cols: 1024 + 256 + 64 + 16

__device__ __forceinline__ unsigned pack2(float a, float b) {
    // truncate-to-bf16 pack: a -> low16, b -> high16
    return (__float_as_uint(a) >> 16) | (__float_as_uint(b) & 0xffff0000u);
}
__device__ __forceinline__ float b2f(unsigned short h) {
    return __uint_as_float(((unsigned)h) << 16);
}
__device__ __forceinline__ unsigned short f2b(float f) {
    return (unsigned short)(__float_as_uint(f) >> 16);
}

// ---- cast hidden fp32 -> bf16 (row-major, k-contig) ----
__global__ void cast_hidden_k(const float* __restrict__ in, unsigned short* __restrict__ out) {
    int idx = (blockIdx.x * 256 + threadIdx.x) * 4;
    float4 v = *(const float4*)(in + idx);
    uint2 o; o.x = pack2(v.x, v.y); o.y = pack2(v.z, v.w);
    *(uint2*)(out + idx) = o;
}

// ---- transpose p [1024][d] -> pT_all rows [rowOff..rowOff+d) x 1024, fp32 ----
__global__ void transpose_k(const float* __restrict__ in, float* __restrict__ out, int d, int rowOff) {
    __shared__ float tile[32][33];
    int tx = threadIdx.x, ty = threadIdx.y;
    int x = blockIdx.x * 32 + tx;
    int ybase = blockIdx.y * 32;
#pragma unroll
    for (int j = 0; j < 4; ++j) {
        int r = ty + j * 8;
        tile[r][tx] = (x < d) ? in[(size_t)(ybase + r) * d + x] : 0.f;
    }
    __syncthreads();
#pragma unroll
    for (int j = 0; j < 4; ++j) {
        int x2 = blockIdx.x * 32 + ty + j * 8;
        if (x2 < d) out[(size_t)(rowOff + x2) * 1024 + ybase + tx] = tile[tx][ty + j * 8];
    }
}

// ---- unified TN GEMM: C[m][n] = sum_k A_bf16[m][k] * B_f32[n][k]
// block: 16 rows x 256 cols, 4 waves split cols (64 each = 4 mfma subtiles)
// epilogue: Cout!=null -> store bf16; else atomicAdd exp(c+bias[n]) into rowsum[m]
__global__ __launch_bounds__(256) void gemm_tn_k(
    const unsigned short* __restrict__ A, int lda,
    const float* __restrict__ B, int ldb,
    const float* __restrict__ bias,
    int N, int K,
    unsigned short* __restrict__ Cout, int ldc,
    float* __restrict__ rowsum)
{
    int tid = threadIdx.x;
    int wave = tid >> 6, lane = tid & 63;
    int l4 = lane & 15, quad = lane >> 4;
    int rbase = blockIdx.x * 16;                 // row tile (fastest-varying blockIdx for L2 reuse of B)
    int cbase = blockIdx.y * 256 + wave * 64;

    f4 acc[4] = {};
    v8s zero8 = {0, 0, 0, 0, 0, 0, 0, 0};

    const unsigned short* arow = A + (size_t)(rbase + l4) * lda;
    int nk = (K + 31) >> 5;
    for (int kt = 0; kt < nk; ++kt) {
        int kk = (kt << 5) + quad * 8;
        v8s a = (kk < K) ? *(const v8s*)(arow + kk) : zero8;
#pragma unroll
        for (int t = 0; t < 4; ++t) {
            int col = cbase + t * 16 + l4;
            v8s b = zero8;
            if ((col < N) && (kk < K)) {
                const float* bp = B + (size_t)col * ldb + kk;
                float4 f0 = *(const float4*)bp;
                float4 f1 = *(const float4*)(bp + 4);
                union { uint4 u; v8s s; } bu;
                bu.u.x = pack2(f0.x, f0.y); bu.u.y = pack2(f0.z, f0.w);
                bu.u.z = pack2(f1.x, f1.y); bu.u.w = pack2(f1.z, f1.w);
                b = bu.s;
            }
            acc[t] = __builtin_amdgcn_mfma_f32_16x16x32_bf16(a, b, acc[t], 0, 0, 0);
        }
    }

    if (Cout) {
#pragma unroll
        for (int t = 0; t < 4; ++t) {
            int col = cbase + t * 16 + l4;
            if (col < N) {
#pragma unroll
                for (int r = 0; r < 4; ++r) {
                    int row = rbase + quad * 4 + r;
                    Cout[(size_t)row * ldc + col] = f2b(acc[t][r]);
                }
            }
        }
    } else {
        float part[4] = {0.f, 0.f, 0.f, 0.f};
#pragma unroll
        for (int t = 0; t < 4; ++t) {
            int col = cbase + t * 16 + l4;
            if (col < N) {
                float bb = bias[col];
#pragma unroll
                for (int r = 0; r < 4; ++r) part[r] += __expf(acc[t][r] + bb);
            }
        }
#pragma unroll
        for (int off = 1; off < 16; off <<= 1) {
#pragma unroll
            for (int r = 0; r < 4; ++r) part[r] += __shfl_xor(part[r], off);
        }
        if (l4 < 4) {
            float v = (l4 == 0) ? part[0] : (l4 == 1) ? part[1] : (l4 == 2) ? part[2] : part[3];
            atomicAdd(&rowsum[rbase + quad * 4 + l4], v);
        }
    }
}

// ---- per-row gathered logits: 3 cluster logits (feed head sumexp) + target/rel logit ----
__global__ __launch_bounds__(256) void gather_k(
    const unsigned short* __restrict__ proj, const int* __restrict__ target,
    const float* __restrict__ cw, const float* __restrict__ cb,
    const float* __restrict__ W0, const float* __restrict__ b0,
    const float* __restrict__ W1, const float* __restrict__ b1,
    const float* __restrict__ W2, const float* __restrict__ b2,
    const float* __restrict__ W3, const float* __restrict__ b3,
    float* __restrict__ rs_head, float* __restrict__ cl, float* __restrict__ tl)
{
    int row = blockIdx.x * 4 + (threadIdx.x >> 6);
    int lane = threadIdx.x & 63;
    const unsigned short* pr = proj + (size_t)row * LDP;

    float c0 = 0.f, c1 = 0.f, c2 = 0.f;
    for (int k = lane; k < 1024; k += 64) {
        float pv = b2f(pr[k]);
        c0 += pv * cw[k]; c1 += pv * cw[1024 + k]; c2 += pv * cw[2048 + k];
    }
#pragma unroll
    for (int off = 1; off < 64; off <<= 1) {
        c0 += __shfl_xor(c0, off); c1 += __shfl_xor(c1, off); c2 += __shfl_xor(c2, off);
    }

    int t = target[row];
    const float* W; const float* bb; int K, off, rel;
    if (t < CUT1)      { W = W0; bb = b0; K = 1024; off = 0;    rel = t; }
    else if (t < CUT2) { W = W1; bb = b1; K = 256;  off = 1024; rel = t - CUT1; }
    else if (t < CUT3) { W = W2; bb = b2; K = 64;   off = 1280; rel = t - CUT2; }
    else               { W = W3; bb = b3; K = 16;   off = 1344; rel = t - CUT3; }
    float acc = 0.f;
    const float* wr = W + (size_t)rel * K;
    for (int k = lane; k < K; k += 64) acc += b2f(pr[off + k]) * wr[k];
#pragma unroll
    for (int o2 = 1; o2 < 64; o2 <<= 1) acc += __shfl_xor(acc, o2);

    if (lane == 0) {
        c0 += cb[0]; c1 += cb[1]; c2 += cb[2];
        cl[row * 3 + 0] = c0; cl[row * 3 + 1] = c1; cl[row * 3 + 2] = c2;
        atomicAdd(&rs_head[row], __expf(c0) + __expf(c1) + __expf(c2));
        tl[row] = acc + bb[rel];
    }
}

// ---- assemble NLL per row ----
__global__ void finalize_k(const int* __restrict__ target, const float* __restrict__ rs,
                           const float* __restrict__ cl, const float* __restrict__ tl,
                           float* __restrict__ out)
{
    int i = blockIdx.x * 256 + threadIdx.x;
    if (i >= NROWS) return;
    int t = target[i];
    float lseh = __logf(rs[i]);
    float lp;
    if (t < CUT1) {
        lp = tl[i] - lseh;
    } else {
        int c = (t < CUT2) ? 0 : (t < CUT3) ? 1 : 2;
        lp = (cl[i * 3 + c] - lseh) + (tl[i] - __logf(rs[(c + 1) * 1024 + i]));
    }
    out[i] = -lp;
}

extern "C" void kernel_launch(void* const* d_in, const int* in_sizes, int n_in,
                              void* d_out, int out_size, void* d_ws, size_t ws_size,
                              hipStream_t stream)
{
    const float* hidden = (const float*)d_in[0];
    const int*   target = (const int*)d_in[1];
    const float* W0 = (const float*)d_in[2];
    const float* b0 = (const float*)d_in[3];
    const float* p0 = (const float*)d_in[4];
    const float* W1 = (const float*)d_in[5];
    const float* b1 = (const float*)d_in[6];
    const float* p1 = (const float*)d_in[7];
    const float* W2 = (const float*)d_in[8];
    const float* b2 = (const float*)d_in[9];
    const float* p2 = (const float*)d_in[10];
    const float* W3 = (const float*)d_in[11];
    const float* b3 = (const float*)d_in[12];
    const float* p3 = (const float*)d_in[13];
    const float* cw = (const float*)d_in[14];
    const float* cb = (const float*)d_in[15];
    float* out = (float*)d_out;

    // workspace layout (10 MB total)
    char* w = (char*)d_ws;
    float*          pT   = (float*)w;                          // [1360][1024] f32   : 5,570,560 B
    unsigned short* hb   = (unsigned short*)(w + 5570560);     // [1024][1024] bf16  : 2,097,152 B
    unsigned short* proj = (unsigned short*)(w + 7667712);     // [1024][1360] bf16  : 2,785,280 B
    float*          rs   = (float*)(w + 10452992);             // 4 x 1024 f32 rowsums
    float*          cl   = (float*)(w + 10469376);             // [1024][3] cluster logits
    float*          tl   = (float*)(w + 10481664);             // [1024] target/rel logit

    hipMemsetAsync(rs, 0, 4 * 1024 * sizeof(float), stream);

    cast_hidden_k<<<1024, 256, 0, stream>>>(hidden, hb);
    dim3 tb(32, 8);
    transpose_k<<<dim3(32, 32), tb, 0, stream>>>(p0, pT, 1024, 0);
    transpose_k<<<dim3(8, 32),  tb, 0, stream>>>(p1, pT, 256, 1024);
    transpose_k<<<dim3(2, 32),  tb, 0, stream>>>(p2, pT, 64, 1280);
    transpose_k<<<dim3(1, 32),  tb, 0, stream>>>(p3, pT, 16, 1344);

    // proj[1024][1360] = hidden @ [p0|p1|p2|p3]   (bf16 out)
    gemm_tn_k<<<dim3(64, 6), 256, 0, stream>>>(hb, 1024, pT, 1024, nullptr,
                                               1360, 1024, proj, LDP, nullptr);
    // head: sumexp over 19997 vocab into rs[0..1023]
    gemm_tn_k<<<dim3(64, 79), 256, 0, stream>>>(proj, LDP, W0, 1024, b0,
                                                CUT1, 1024, nullptr, 0, rs);
    // tails: sumexp into rs[1024*i ..]
    gemm_tn_k<<<dim3(64, 79), 256, 0, stream>>>(proj + 1024, LDP, W1, 256, b1,
                                                20000, 256, nullptr, 0, rs + 1024);
    gemm_tn_k<<<dim3(64, 625), 256, 0, stream>>>(proj + 1280, LDP, W2, 64, b2,
                                                 160000, 64, nullptr, 0, rs + 2048);
    gemm_tn_k<<<dim3(64, 265), 256, 0, stream>>>(proj + 1344, LDP, W3, 16, b3,
                                                 67738, 16, nullptr, 0, rs + 3072);

    gather_k<<<256, 256, 0, stream>>>(proj, target, cw, cb,
                                      W0, b0, W1, b1, W2, b2, W3, b3,
                                      rs, cl, tl);
    finalize_k<<<4, 256, 0, stream>>>(target, rs, cl, tl, out);
}

// Round 2
// 497.714 us; speedup vs baseline: 2.6433x; 2.6433x over previous
//
#include <hip/hip_runtime.h>
#include <stdint.h>

typedef short v8s __attribute__((ext_vector_type(8)));
typedef float f4 __attribute__((ext_vector_type(4)));
typedef unsigned short u16;
typedef unsigned int u32;

#define CUT1 19997
#define CUT2 39997
#define CUT3 199997
#define NROWS 1024
#define LDP 1360   // packed proj cols: 1024 + 256 + 64 + 16

__device__ __forceinline__ u32 pack2(float a, float b) {
    return (__float_as_uint(a) >> 16) | (__float_as_uint(b) & 0xffff0000u);
}
__device__ __forceinline__ float b2f(u16 h) { return __uint_as_float(((u32)h) << 16); }
__device__ __forceinline__ u16 f2b(float f) { return (u16)(__float_as_uint(f) >> 16); }

__device__ __forceinline__ void gload16(const void* g, void* l) {
    __builtin_amdgcn_global_load_lds(
        (const __attribute__((address_space(1))) u32*)g,
        (__attribute__((address_space(3))) u32*)l, 16, 0, 0);
}

// ======================= fp32 -> bf16 casts =======================
__global__ void cast_bf16_k(const float* __restrict__ in, u16* __restrict__ out, int n8) {
    int i = blockIdx.x * 256 + threadIdx.x;
    if (i >= n8) return;
    const float4* p = (const float4*)(in + (size_t)i * 8);
    float4 a = p[0], b = p[1];
    uint4 o = { pack2(a.x, a.y), pack2(a.z, a.w), pack2(b.x, b.y), pack2(b.z, b.w) };
    *(uint4*)(out + (size_t)i * 8) = o;
}

// W3 [67738][16] fp32 -> bf16 zero-padded to ld=32 (MFMA needs K=32)
__global__ void cast_w3_k(const float* __restrict__ in, u16* __restrict__ out) {
    int r = blockIdx.x * 256 + threadIdx.x;
    if (r >= 67738) return;
    const float4* p = (const float4*)(in + (size_t)r * 16);
    float4 a = p[0], b = p[1], c = p[2], d = p[3];
    uint4 o0 = { pack2(a.x, a.y), pack2(a.z, a.w), pack2(b.x, b.y), pack2(b.z, b.w) };
    uint4 o1 = { pack2(c.x, c.y), pack2(c.z, c.w), pack2(d.x, d.y), pack2(d.z, d.w) };
    uint4 z = { 0, 0, 0, 0 };
    uint4* q = (uint4*)(out + (size_t)r * 32);
    q[0] = o0; q[1] = o1; q[2] = z; q[3] = z;
}

// transpose p [1024][d] fp32 -> bf16 rows [rowOff..rowOff+d) x 1024
__global__ void transpose_b_k(const float* __restrict__ in, u16* __restrict__ out, int d, int rowOff) {
    __shared__ float tile[32][33];
    int tx = threadIdx.x, ty = threadIdx.y;
    int x = blockIdx.x * 32 + tx;
    int ybase = blockIdx.y * 32;
#pragma unroll
    for (int j = 0; j < 4; ++j) {
        int r = ty + j * 8;
        tile[r][tx] = (x < d) ? in[(size_t)(ybase + r) * d + x] : 0.f;
    }
    __syncthreads();
#pragma unroll
    for (int j = 0; j < 4; ++j) {
        int x2 = blockIdx.x * 32 + ty + j * 8;
        if (x2 < d) out[(size_t)(rowOff + x2) * 1024 + ybase + tx] = f2b(tile[tx][ty + j * 8]);
    }
}

// ======================= main MFMA GEMM (m97 structure) =======================
// TN: C[m][n] = sum_k A_bf16[m][k] * B_bf16[n][k]; BM=BN=128, BK=32; 4 waves 2x2.
// MODE 0: store bf16 C. MODE 1: rowsum[m] += sum_n exp(C[m][n] + bias[n]).
// count: if non-null, early-exit row-blocks with rbase >= roundup(*count,128).
template<int MODE>
__global__ __launch_bounds__(256) void gemm_k(
    const u16* __restrict__ A, int lda,
    const u16* __restrict__ B, int ldb,
    const float* __restrict__ bias, int N, int K,
    u16* __restrict__ Cout, int ldc,
    float* __restrict__ rowsum, const int* __restrict__ count)
{
    __shared__ __align__(16) u16 As[128 * 32];
    __shared__ __align__(16) u16 Bs[128 * 32];

    const int tid = threadIdx.x;
    const int rbase = blockIdx.x * 128, cbase = blockIdx.y * 128;
    if (count) {
        int cnt = *count;
        if (rbase >= ((cnt + 127) & ~127)) return;
    }

    const int wave = tid >> 6, lane = tid & 63;
    const int l4 = lane & 15, quad = lane >> 4;
    const int wr = (wave >> 1) * 64, wc = (wave & 1) * 64;

    // staging: 512 slots of 16B per tile; thread covers slots {tid, 256+tid}
    const int srow = tid >> 2, sseg = tid & 3;
    const u16* Ag0 = A + (size_t)(rbase + srow) * lda + sseg * 8;
    const u16* Ag1 = Ag0 + (size_t)64 * lda;
    int bc0 = cbase + srow;      if (bc0 >= N) bc0 = N - 1;
    int bc1 = cbase + 64 + srow; if (bc1 >= N) bc1 = N - 1;
    const u16* Bg0 = B + (size_t)bc0 * ldb + sseg * 8;
    const u16* Bg1 = B + (size_t)bc1 * ldb + sseg * 8;
    u16* lA0 = &As[tid * 8]; u16* lA1 = &As[(256 + tid) * 8];
    u16* lB0 = &Bs[tid * 8]; u16* lB1 = &Bs[(256 + tid) * 8];

    const u16* Afr = &As[(wr + l4) * 32 + quad * 8];
    const u16* Bfr = &Bs[(wc + l4) * 32 + quad * 8];

    f4 acc[4][4] = {};
    const int nk = K >> 5;
    for (int kt = 0; kt < nk; ++kt) {
        const int kk = kt << 5;
        gload16(Ag0 + kk, lA0);
        gload16(Ag1 + kk, lA1);
        gload16(Bg0 + kk, lB0);
        gload16(Bg1 + kk, lB1);
        __syncthreads();
        v8s af[4], bf[4];
#pragma unroll
        for (int r = 0; r < 4; ++r) af[r] = *(const v8s*)(Afr + r * 512);
#pragma unroll
        for (int c = 0; c < 4; ++c) bf[c] = *(const v8s*)(Bfr + c * 512);
#pragma unroll
        for (int r = 0; r < 4; ++r)
#pragma unroll
            for (int c = 0; c < 4; ++c)
                acc[r][c] = __builtin_amdgcn_mfma_f32_16x16x32_bf16(af[r], bf[c], acc[r][c], 0, 0, 0);
        __syncthreads();
    }

    if (MODE == 0) {
#pragma unroll
        for (int c = 0; c < 4; ++c) {
            int col = cbase + wc + c * 16 + l4;
            if (col < N) {
#pragma unroll
                for (int r = 0; r < 4; ++r)
#pragma unroll
                    for (int g = 0; g < 4; ++g) {
                        int row = rbase + wr + r * 16 + quad * 4 + g;
                        Cout[(size_t)row * ldc + col] = f2b(acc[r][c][g]);
                    }
            }
        }
    } else {
        float part[4][4];
#pragma unroll
        for (int r = 0; r < 4; ++r)
#pragma unroll
            for (int g = 0; g < 4; ++g) part[r][g] = 0.f;
#pragma unroll
        for (int c = 0; c < 4; ++c) {
            int col = cbase + wc + c * 16 + l4;
            if (col < N) {
                float bb = bias[col];
#pragma unroll
                for (int r = 0; r < 4; ++r)
#pragma unroll
                    for (int g = 0; g < 4; ++g)
                        part[r][g] += __expf(acc[r][c][g] + bb);
            }
        }
#pragma unroll
        for (int off = 1; off < 16; off <<= 1)
#pragma unroll
            for (int r = 0; r < 4; ++r)
#pragma unroll
                for (int g = 0; g < 4; ++g)
                    part[r][g] += __shfl_xor(part[r][g], off);
        float v = part[0][0];
#pragma unroll
        for (int r = 0; r < 4; ++r)
#pragma unroll
            for (int g = 0; g < 4; ++g)
                if (l4 == r * 4 + g) v = part[r][g];
        int row = rbase + wr + (l4 >> 2) * 16 + quad * 4 + (l4 & 3);
        atomicAdd(&rowsum[row], v);
    }
}

// ======================= compaction =======================
__global__ void classify_k(const int* __restrict__ target, int* __restrict__ cnt,
                           int* __restrict__ slot) {
    int r = blockIdx.x * 256 + threadIdx.x;
    if (r >= NROWS) return;
    int t = target[r];
    int c = (t < CUT1) ? -1 : (t < CUT2) ? 0 : (t < CUT3) ? 1 : 2;
    int s = -1;
    if (c >= 0) s = atomicAdd(&cnt[c], 1);
    slot[r] = s;
}

__global__ void gatherA_k(const u16* __restrict__ proj_, const int* __restrict__ slot,
                          const int* __restrict__ target,
                          u16* __restrict__ Ac1, u16* __restrict__ Ac2, u16* __restrict__ Ac3)
{
    int r = blockIdx.x;
    int s = slot[r];
    if (s < 0) return;
    int tv = target[r];
    int lane = threadIdx.x;
    const u16* pr = proj_ + (size_t)r * LDP;
    if (tv < CUT2) {
        ((ushort4*)(Ac1 + (size_t)s * 256))[lane] = ((const ushort4*)(pr + 1024))[lane];
    } else if (tv < CUT3) {
        Ac2[(size_t)s * 64 + lane] = pr[1280 + lane];
    } else {
        if (lane < 16) Ac3[(size_t)s * 32 + lane] = pr[1344 + lane];
    }
}

// ======================= per-row gathered logits =======================
__global__ __launch_bounds__(256) void gather_k(
    const u16* __restrict__ proj, const int* __restrict__ target,
    const float* __restrict__ cw, const float* __restrict__ cb,
    const float* __restrict__ W0, const float* __restrict__ b0,
    const float* __restrict__ W1, const float* __restrict__ b1,
    const float* __restrict__ W2, const float* __restrict__ b2,
    const float* __restrict__ W3, const float* __restrict__ b3,
    float* __restrict__ rs_head, float* __restrict__ cl, float* __restrict__ tl)
{
    int row = blockIdx.x * 4 + (threadIdx.x >> 6);
    int lane = threadIdx.x & 63;
    const u16* pr = proj + (size_t)row * LDP;

    float c0 = 0.f, c1 = 0.f, c2 = 0.f;
    for (int k = lane; k < 1024; k += 64) {
        float pv = b2f(pr[k]);
        c0 += pv * cw[k]; c1 += pv * cw[1024 + k]; c2 += pv * cw[2048 + k];
    }
#pragma unroll
    for (int off = 1; off < 64; off <<= 1) {
        c0 += __shfl_xor(c0, off); c1 += __shfl_xor(c1, off); c2 += __shfl_xor(c2, off);
    }

    int t = target[row];
    const float* W; const float* bb; int K, off, rel;
    if (t < CUT1)      { W = W0; bb = b0; K = 1024; off = 0;    rel = t; }
    else if (t < CUT2) { W = W1; bb = b1; K = 256;  off = 1024; rel = t - CUT1; }
    else if (t < CUT3) { W = W2; bb = b2; K = 64;   off = 1280; rel = t - CUT2; }
    else               { W = W3; bb = b3; K = 16;   off = 1344; rel = t - CUT3; }
    float acc = 0.f;
    const float* wr = W + (size_t)rel * K;
    for (int k = lane; k < K; k += 64) acc += b2f(pr[off + k]) * wr[k];
#pragma unroll
    for (int o2 = 1; o2 < 64; o2 <<= 1) acc += __shfl_xor(acc, o2);

    if (lane == 0) {
        c0 += cb[0]; c1 += cb[1]; c2 += cb[2];
        cl[row * 3 + 0] = c0; cl[row * 3 + 1] = c1; cl[row * 3 + 2] = c2;
        atomicAdd(&rs_head[row], __expf(c0) + __expf(c1) + __expf(c2));
        tl[row] = acc + bb[rel];
    }
}

// ======================= finalize =======================
__global__ void finalize_k(const int* __restrict__ target, const float* __restrict__ rs,
                           const int* __restrict__ slot,
                           const float* __restrict__ cl, const float* __restrict__ tl,
                           float* __restrict__ out)
{
    int i = blockIdx.x * 256 + threadIdx.x;
    if (i >= NROWS) return;
    int t = target[i];
    float lseh = __logf(rs[i]);
    float lp;
    if (t < CUT1) lp = tl[i] - lseh;
    else {
        int c = (t < CUT2) ? 0 : (t < CUT3) ? 1 : 2;
        lp = (cl[i * 3 + c] - lseh) + (tl[i] - __logf(rs[(c + 1) * 1024 + slot[i]]));
    }
    out[i] = -lp;
}

// ======================= fallback path (round-1, verified) =======================
__global__ void transpose_f_k(const float* __restrict__ in, float* __restrict__ out, int d, int rowOff) {
    __shared__ float tile[32][33];
    int tx = threadIdx.x, ty = threadIdx.y;
    int x = blockIdx.x * 32 + tx;
    int ybase = blockIdx.y * 32;
#pragma unroll
    for (int j = 0; j < 4; ++j) {
        int r = ty + j * 8;
        tile[r][tx] = (x < d) ? in[(size_t)(ybase + r) * d + x] : 0.f;
    }
    __syncthreads();
#pragma unroll
    for (int j = 0; j < 4; ++j) {
        int x2 = blockIdx.x * 32 + ty + j * 8;
        if (x2 < d) out[(size_t)(rowOff + x2) * 1024 + ybase + tx] = tile[tx][ty + j * 8];
    }
}

__global__ __launch_bounds__(256) void gemm_tn_k(
    const u16* __restrict__ A, int lda,
    const float* __restrict__ B, int ldb,
    const float* __restrict__ bias, int N, int K,
    u16* __restrict__ Cout, int ldc, float* __restrict__ rowsum)
{
    int tid = threadIdx.x;
    int wave = tid >> 6, lane = tid & 63;
    int l4 = lane & 15, quad = lane >> 4;
    int rbase = blockIdx.x * 16;
    int cbase = blockIdx.y * 256 + wave * 64;

    f4 acc[4] = {};
    v8s zero8 = {0, 0, 0, 0, 0, 0, 0, 0};
    const u16* arow = A + (size_t)(rbase + l4) * lda;
    int nk = (K + 31) >> 5;
    for (int kt = 0; kt < nk; ++kt) {
        int kk = (kt << 5) + quad * 8;
        v8s a = (kk < K) ? *(const v8s*)(arow + kk) : zero8;
#pragma unroll
        for (int t = 0; t < 4; ++t) {
            int col = cbase + t * 16 + l4;
            v8s b = zero8;
            if ((col < N) && (kk < K)) {
                const float* bp = B + (size_t)col * ldb + kk;
                float4 f0 = *(const float4*)bp;
                float4 f1 = *(const float4*)(bp + 4);
                union { uint4 u; v8s s; } bu;
                bu.u.x = pack2(f0.x, f0.y); bu.u.y = pack2(f0.z, f0.w);
                bu.u.z = pack2(f1.x, f1.y); bu.u.w = pack2(f1.z, f1.w);
                b = bu.s;
            }
            acc[t] = __builtin_amdgcn_mfma_f32_16x16x32_bf16(a, b, acc[t], 0, 0, 0);
        }
    }
    if (Cout) {
#pragma unroll
        for (int t = 0; t < 4; ++t) {
            int col = cbase + t * 16 + l4;
            if (col < N) {
#pragma unroll
                for (int r = 0; r < 4; ++r)
                    Cout[(size_t)(rbase + quad * 4 + r) * ldc + col] = f2b(acc[t][r]);
            }
        }
    } else {
        float part[4] = {0.f, 0.f, 0.f, 0.f};
#pragma unroll
        for (int t = 0; t < 4; ++t) {
            int col = cbase + t * 16 + l4;
            if (col < N) {
                float bb = bias[col];
#pragma unroll
                for (int r = 0; r < 4; ++r) part[r] += __expf(acc[t][r] + bb);
            }
        }
#pragma unroll
        for (int off = 1; off < 16; off <<= 1)
#pragma unroll
            for (int r = 0; r < 4; ++r) part[r] += __shfl_xor(part[r], off);
        if (l4 < 4) {
            float v = (l4 == 0) ? part[0] : (l4 == 1) ? part[1] : (l4 == 2) ? part[2] : part[3];
            atomicAdd(&rowsum[rbase + quad * 4 + l4], v);
        }
    }
}

__global__ void finalize_full_k(const int* __restrict__ target, const float* __restrict__ rs,
                                const float* __restrict__ cl, const float* __restrict__ tl,
                                float* __restrict__ out)
{
    int i = blockIdx.x * 256 + threadIdx.x;
    if (i >= NROWS) return;
    int t = target[i];
    float lseh = __logf(rs[i]);
    float lp;
    if (t < CUT1) lp = tl[i] - lseh;
    else {
        int c = (t < CUT2) ? 0 : (t < CUT3) ? 1 : 2;
        lp = (cl[i * 3 + c] - lseh) + (tl[i] - __logf(rs[(c + 1) * 1024 + i]));
    }
    out[i] = -lp;
}

// ======================= host =======================
extern "C" void kernel_launch(void* const* d_in, const int* in_sizes, int n_in,
                              void* d_out, int out_size, void* d_ws, size_t ws_size,
                              hipStream_t stream)
{
    const float* hidden = (const float*)d_in[0];
    const int*   target = (const int*)d_in[1];
    const float* W0 = (const float*)d_in[2];
    const float* b0 = (const float*)d_in[3];
    const float* p0 = (const float*)d_in[4];
    const float* W1 = (const float*)d_in[5];
    const float* b1 = (const float*)d_in[6];
    const float* p1 = (const float*)d_in[7];
    const float* W2 = (const float*)d_in[8];
    const float* b2 = (const float*)d_in[9];
    const float* p2 = (const float*)d_in[10];
    const float* W3 = (const float*)d_in[11];
    const float* b3 = (const float*)d_in[12];
    const float* p3 = (const float*)d_in[13];
    const float* cw = (const float*)d_in[14];
    const float* cb = (const float*)d_in[15];
    float* out = (float*)d_out;
    char* w = (char*)d_ws;
    dim3 tb(32, 8);

    if (ws_size >= 85000000ull) {
        // ---- bf16-precast fast path ----
        u16*   hb   = (u16*)(w + 0);             // 1024x1024 bf16
        u16*   pTb  = (u16*)(w + 2097152);       // [1360][1024] bf16
        u16*   proj = (u16*)(w + 4882432);       // [1024][1360] bf16
        u16*   W0b  = (u16*)(w + 7667712);       // 19997x1024
        u16*   W1b  = (u16*)(w + 48621568);      // 20000x256
        u16*   W2b  = (u16*)(w + 58861568);      // 160000x64
        u16*   W3b  = (u16*)(w + 79341568);      // 67738x32 (zero-padded)
        u16*   Ac1  = (u16*)(w + 83676800);      // 1024x256
        u16*   Ac2  = (u16*)(w + 84201088);      // 1024x64
        u16*   Ac3  = (u16*)(w + 84332160);      // 1024x32
        float* rs   = (float*)(w + 84397696);    // 4x1024
        float* cl   = (float*)(w + 84414080);    // 1024x3
        float* tl   = (float*)(w + 84426368);    // 1024
        int*   cnt  = (int*)(w + 84430464);      // 3
        int*   slot = (int*)(w + 84430480);      // 1024

        hipMemsetAsync(w + 83676800, 0, 761872, stream);  // Ac1..slot

        cast_bf16_k<<<512, 256, 0, stream>>>(hidden, hb, 131072);
        transpose_b_k<<<dim3(32, 32), tb, 0, stream>>>(p0, pTb, 1024, 0);
        transpose_b_k<<<dim3(8, 32),  tb, 0, stream>>>(p1, pTb, 256, 1024);
        transpose_b_k<<<dim3(2, 32),  tb, 0, stream>>>(p2, pTb, 64, 1280);
        transpose_b_k<<<dim3(1, 32),  tb, 0, stream>>>(p3, pTb, 16, 1344);
        cast_bf16_k<<<9999, 256, 0, stream>>>(W0, W0b, 2559616);
        cast_bf16_k<<<2500, 256, 0, stream>>>(W1, W1b, 640000);
        cast_bf16_k<<<5000, 256, 0, stream>>>(W2, W2b, 1280000);
        cast_w3_k<<<265, 256, 0, stream>>>(W3, W3b);

        // proj = hidden @ [p0|p1|p2|p3], bf16 out
        gemm_k<0><<<dim3(8, 11), 256, 0, stream>>>(hb, 1024, pTb, 1024, nullptr,
                                                   1360, 1024, proj, LDP, nullptr, nullptr);
        classify_k<<<4, 256, 0, stream>>>(target, cnt, slot);
        gatherA_k<<<1024, 64, 0, stream>>>(proj, slot, target, Ac1, Ac2, Ac3);

        // head sumexp (all rows)
        gemm_k<1><<<dim3(8, 157), 256, 0, stream>>>(proj, LDP, W0b, 1024, b0,
                                                    CUT1, 1024, nullptr, 0, rs, nullptr);
        // tails: compacted rows, early-exit via cnt
        gemm_k<1><<<dim3(8, 157), 256, 0, stream>>>(Ac1, 256, W1b, 256, b1,
                                                    20000, 256, nullptr, 0, rs + 1024, cnt + 0);
        gemm_k<1><<<dim3(8, 1250), 256, 0, stream>>>(Ac2, 64, W2b, 64, b2,
                                                     160000, 64, nullptr, 0, rs + 2048, cnt + 1);
        gemm_k<1><<<dim3(8, 530), 256, 0, stream>>>(Ac3, 32, W3b, 32, b3,
                                                    67738, 32, nullptr, 0, rs + 3072, cnt + 2);

        gather_k<<<256, 256, 0, stream>>>(proj, target, cw, cb,
                                          W0, b0, W1, b1, W2, b2, W3, b3, rs, cl, tl);
        finalize_k<<<4, 256, 0, stream>>>(target, rs, slot, cl, tl, out);
    } else {
        // ---- round-1 verified fallback ----
        float* pT   = (float*)w;                          // [1360][1024] f32
        u16*   hb   = (u16*)(w + 5570560);                // [1024][1024] bf16
        u16*   proj = (u16*)(w + 7667712);                // [1024][1360] bf16
        float* rs   = (float*)(w + 10452992);
        float* cl   = (float*)(w + 10469376);
        float* tl   = (float*)(w + 10481664);

        hipMemsetAsync(rs, 0, 4 * 1024 * sizeof(float), stream);
        cast_bf16_k<<<512, 256, 0, stream>>>(hidden, hb, 131072);
        transpose_f_k<<<dim3(32, 32), tb, 0, stream>>>(p0, pT, 1024, 0);
        transpose_f_k<<<dim3(8, 32),  tb, 0, stream>>>(p1, pT, 256, 1024);
        transpose_f_k<<<dim3(2, 32),  tb, 0, stream>>>(p2, pT, 64, 1280);
        transpose_f_k<<<dim3(1, 32),  tb, 0, stream>>>(p3, pT, 16, 1344);

        gemm_tn_k<<<dim3(64, 6), 256, 0, stream>>>(hb, 1024, pT, 1024, nullptr,
                                                   1360, 1024, proj, LDP, nullptr);
        gemm_tn_k<<<dim3(64, 79), 256, 0, stream>>>(proj, LDP, W0, 1024, b0,
                                                    CUT1, 1024, nullptr, 0, rs);
        gemm_tn_k<<<dim3(64, 79), 256, 0, stream>>>(proj + 1024, LDP, W1, 256, b1,
                                                    20000, 256, nullptr, 0, rs + 1024);
        gemm_tn_k<<<dim3(64, 625), 256, 0, stream>>>(proj + 1280, LDP, W2, 64, b2,
                                                     160000, 64, nullptr, 0, rs + 2048);
        gemm_tn_k<<<dim3(64, 265), 256, 0, stream>>>(proj + 1344, LDP, W3, 16, b3,
                                                     67738, 16, nullptr, 0, rs + 3072);

        gather_k<<<256, 256, 0, stream>>>(proj, target, cw, cb,
                                          W0, b0, W1, b1, W2, b2, W3, b3, rs, cl, tl);
        finalize_full_k<<<4, 256, 0, stream>>>(target, rs, cl, tl, out);
    }
}